// Round 3
// baseline (386.905 us; speedup 1.0000x reference)
//
#include <hip/hip_runtime.h>

#define N_NODES 50000
#define N_EDGES 1000000
#define EMB     64
#define HID     128
#define NLAYER  3
#define NGRAPH  250
#define XFD     7
#define EFD     5
#define BN_EPS  1e-5f

// two-level counting sort geometry
#define BKT_SH 8
#define BKT_SZ 256
#define NBKT   ((N_NODES + BKT_SZ - 1) / BKT_SZ)  // 196
#define CHKE   4096
#define NCHK   ((N_EDGES + CHKE - 1) / CHKE)      // 245
#define CNTM   (NBKT * NCHK)                      // 48020
#define INPB   ((((N_NODES + 1) * EMB) + 255) / 256)   // 12501
#define PACKB  ((NLAYER * 2 * EMB * HID + 255) / 256)  // 192

typedef short bf8_t __attribute__((ext_vector_type(8)));   // 8 bf16 (4 VGPRs)
typedef float f4_t  __attribute__((ext_vector_type(4)));   // MFMA acc

union FragU {
    uint4 q;
    bf8_t v;
    unsigned short u[8];
};

__device__ __forceinline__ void atomAddF(float* p, float v) {
    __hip_atomic_fetch_add(p, v, __ATOMIC_RELAXED, __HIP_MEMORY_SCOPE_AGENT);
}

__device__ __forceinline__ unsigned short f2bf(float f) {
    unsigned int u = __float_as_uint(f);
    u += 0x7fffu + ((u >> 16) & 1u);
    return (unsigned short)(u >> 16);
}
__device__ __forceinline__ float bf2f(unsigned short s) {
    return __uint_as_float(((unsigned int)s) << 16);
}
__device__ __forceinline__ float4 bf4(ushort4 u) {
    return make_float4(bf2f(u.x), bf2f(u.y), bf2f(u.z), bf2f(u.w));
}

// Fused one-time prep: h = x@xW+xb (+ zero row N_NODES), W1/W2 pack into
// MFMA B-frag order, stats zero. Block-range dispatch kills 2 launches + memset.
__global__ void k_prep(const float* __restrict__ x, const float* __restrict__ xW,
                       const float* __restrict__ xb, unsigned short* __restrict__ h,
                       const float* __restrict__ W1, const float* __restrict__ W2,
                       unsigned short* __restrict__ pw1, unsigned short* __restrict__ pw2,
                       float* __restrict__ stats) {
    int bid = blockIdx.x;
    if (bid < INPB) {
        int gid = bid * 256 + threadIdx.x;
        if (gid >= (N_NODES + 1) * EMB) return;
        int n = gid >> 6, f = gid & 63;
        if (n == N_NODES) { h[gid] = 0; return; }
        float acc = xb[f];
#pragma unroll
        for (int k = 0; k < XFD; ++k) acc = fmaf(x[n * XFD + k], xW[k * EMB + f], acc);
        h[gid] = f2bf(acc);
    } else if (bid < INPB + PACKB) {
        int gid = (bid - INPB) * 256 + threadIdx.x;    // 3*16384 total
        int layer = gid >> 14;
        int r = gid & 16383;
        if (layer >= NLAYER) return;
        if (r < 8192) {
            int p = r;
            int j = p & 7, lane = (p >> 3) & 63, ts = p >> 9;  // ts<16
            int t = ts >> 1, s = ts & 1;
            int k = 32 * s + 8 * (lane >> 4) + j;
            int n = 16 * t + (lane & 15);
            pw1[layer * 8192 + p] = f2bf(W1[layer * EMB * HID + k * HID + n]);
        } else {
            int p = r - 8192;
            int j = p & 7, lane = (p >> 3) & 63, ts = p >> 9;  // ts<16
            int t = ts >> 2, s = ts & 3;
            int k = 32 * s + 8 * (lane >> 4) + j;
            int n = 16 * t + (lane & 15);
            pw2[layer * 8192 + p] = f2bf(W2[layer * HID * EMB + k * EMB + n]);
        }
    } else {
        for (int i = threadIdx.x; i < NLAYER * 2 * EMB; i += 256) stats[i] = 0.f;
    }
}

// ---- phase A: per-chunk coarse-bucket histogram ----
__global__ __launch_bounds__(256) void k_binA(const int* __restrict__ dst,
                                              int* __restrict__ cntmat) {
    __shared__ int hist[NBKT];
    int tid = threadIdx.x, c = blockIdx.x;
    for (int i = tid; i < NBKT; i += 256) hist[i] = 0;
    __syncthreads();
    int e0 = c * CHKE, e1 = min(e0 + CHKE, N_EDGES);
    for (int i = e0 + tid; i < e1; i += 256) atomicAdd(&hist[dst[i] >> BKT_SH], 1);
    __syncthreads();
    for (int b = tid; b < NBKT; b += 256) cntmat[b * NCHK + c] = hist[b];
}

// ---- single-block chained exclusive scan of CNTM ints (replaces 3 kernels).
// 47 rounds x 1024 threads; ~4us, but saves 2 dispatch overheads.
__global__ __launch_bounds__(1024) void k_scan(const int* __restrict__ in,
                                               int* __restrict__ out) {
    __shared__ int wsum[16];
    int tid = threadIdx.x, lane = tid & 63, wid = tid >> 6;
    int carry = 0;
    for (int base = 0; base < CNTM; base += 1024) {
        int i = base + tid;
        int v = (i < CNTM) ? in[i] : 0;
        int x = v;
#pragma unroll
        for (int off = 1; off < 64; off <<= 1) {
            int y = __shfl_up(x, off);
            if (lane >= off) x += y;
        }
        if (lane == 63) wsum[wid] = x;
        __syncthreads();
        int woff = 0, tot = 0;
#pragma unroll
        for (int w = 0; w < 16; ++w) {
            int s = wsum[w];
            if (w < wid) woff += s;
            tot += s;
        }
        if (i < CNTM) out[i] = carry + woff + x - v;
        carry += tot;
        __syncthreads();
    }
}

// ---- phase C: coarse scatter of packed {src, d_local<<20|eid} ----
__global__ __launch_bounds__(256) void k_binC(const int* __restrict__ src,
                                              const int* __restrict__ dst,
                                              const int* __restrict__ off2,
                                              int2* __restrict__ bufSD) {
    __shared__ int cur[NBKT];
    int tid = threadIdx.x, c = blockIdx.x;
    for (int b = tid; b < NBKT; b += 256) cur[b] = off2[b * NCHK + c];
    __syncthreads();
    int e0 = c * CHKE, e1 = min(e0 + CHKE, N_EDGES);
    for (int i = e0 + tid; i < e1; i += 256) {
        int d = dst[i];
        int b = d >> BKT_SH;
        int p = atomicAdd(&cur[b], 1);
        bufSD[p] = make_int2(src[i], ((d & (BKT_SZ - 1)) << 20) | i);
    }
}

// ---- phase D: per-bucket fine sort -> csr + csrE + rowstart ----
__global__ __launch_bounds__(256) void k_binD(const int2* __restrict__ bufSD,
                                              const int* __restrict__ off2,
                                              int* __restrict__ csr,
                                              int* __restrict__ csrE,
                                              int* __restrict__ rowstart) {
    __shared__ int hist[BKT_SZ];
    __shared__ int cur[BKT_SZ];
    __shared__ int wtot[4];
    int tid = threadIdx.x, b = blockIdx.x;
    int bstart = off2[b * NCHK];
    int bend = (b + 1 < NBKT) ? off2[(b + 1) * NCHK] : N_EDGES;
    hist[tid] = 0;
    __syncthreads();
    for (int j = bstart + tid; j < bend; j += 256)
        atomicAdd(&hist[bufSD[j].y >> 20], 1);
    __syncthreads();
    int lane = tid & 63, wid = tid >> 6;
    int v = hist[tid], x = v;
#pragma unroll
    for (int off = 1; off < 64; off <<= 1) {
        int y = __shfl_up(x, off);
        if (lane >= off) x += y;
    }
    if (lane == 63) wtot[wid] = x;
    __syncthreads();
    int woff = 0;
    for (int w = 0; w < wid; ++w) woff += wtot[w];
    int ex = woff + x - v;
    cur[tid] = ex;
    int node = b * BKT_SZ + tid;
    if (node < N_NODES) rowstart[node] = bstart + ex;
    if (b == NBKT - 1 && tid == 0) rowstart[N_NODES] = N_EDGES;
    __syncthreads();
    for (int j = bstart + tid; j < bend; j += 256) {
        int2 t = bufSD[j];
        int local = t.y >> 20;
        int p = atomicAdd(&cur[local], 1);
        csr[bstart + p] = t.x;
        csrE[bstart + p] = t.y & 0xFFFFF;
    }
}

// agg(f32): wave handles 2 consecutive nodes (25000 waves -> deeper TLP than
// 4/wave; gather is latency-bound). uint4 gathers: row of 64 bf16 read by 8
// lanes, 8 edges per load instruction, 4/8 loads unconditionally in flight.
// Invalid edge slots redirect to the all-zero row h[N_NODES].
// L0: edge-feature aggregation fused into the edge loop (each lane loads its
// own edge's 5 ea floats, predicated); butterfly-reduced at node end, written
// to aggE for layers 1-2 and consumed inline. Kills the k_aggE kernel.
#define ACC8(v)                                                         \
    do {                                                                \
        f0 += __uint_as_float((v).x << 16);                             \
        f1 += __uint_as_float((v).x & 0xffff0000u);                     \
        f2 += __uint_as_float((v).y << 16);                             \
        f3 += __uint_as_float((v).y & 0xffff0000u);                     \
        f4 += __uint_as_float((v).z << 16);                             \
        f5 += __uint_as_float((v).z & 0xffff0000u);                     \
        f6 += __uint_as_float((v).w << 16);                             \
        f7 += __uint_as_float((v).w & 0xffff0000u);                     \
    } while (0)

template <int L0>
__global__ __launch_bounds__(256) void k_agg(const unsigned short* __restrict__ h,
                                             float* __restrict__ agg,
                                             const int* __restrict__ rowstart,
                                             const int* __restrict__ csr,
                                             const int* __restrict__ csrE,
                                             const float* __restrict__ ea,
                                             float* __restrict__ aggE,
                                             const float* __restrict__ eWl,
                                             const float* __restrict__ ebl) {
    int wave = (blockIdx.x * 256 + threadIdx.x) >> 6;
    int lane = threadIdx.x & 63;
    int nbase = wave * 2;
    if (nbase >= N_NODES) return;
    int lg3 = lane >> 3, lq3 = lane & 7;   // edge slot / uint4 chunk
    int lg = lane >> 4, lq = lane & 15;    // epilogue layout (float4 per lq)
    const uint4* hb8 = (const uint4*)h;        // 8 uint4 per 64-bf16 row
    const ushort4* hb4 = (const ushort4*)h;    // 16 ushort4 per row
    const float4* eW4 = (const float4*)eWl;
    float4 ew0 = eW4[lq], ew1 = eW4[16 + lq], ew2 = eW4[32 + lq],
           ew3 = eW4[48 + lq], ew4 = eW4[64 + lq];
    float4 eb4 = ((const float4*)ebl)[lq];
    int nend = min(nbase + 2, N_NODES);
    for (int n = nbase; n < nend; ++n) {
        int j0 = rowstart[n], j1 = rowstart[n + 1];
        float f0 = 0.f, f1 = 0.f, f2 = 0.f, f3 = 0.f,
              f4 = 0.f, f5 = 0.f, f6 = 0.f, f7 = 0.f;
        float e0 = 0.f, e1 = 0.f, e2 = 0.f, e3 = 0.f, e4 = 0.f;
        for (int j = j0; j < j1;) {
            int take = j1 - j;
            if (take > 64) take = 64;
            int myid = (lane < take) ? csr[j + lane] : N_NODES;  // zero row
            if (L0) {
                if (lane < take) {
                    const float* p = ea + (size_t)csrE[j + lane] * EFD;
                    e0 += p[0]; e1 += p[1]; e2 += p[2]; e3 += p[3]; e4 += p[4];
                }
            }
            int s0 = __shfl(myid, lg3);
            int s1 = __shfl(myid, 8 + lg3);
            int s2 = __shfl(myid, 16 + lg3);
            int s3 = __shfl(myid, 24 + lg3);
            uint4 v0 = hb8[(size_t)s0 * 8 + lq3];
            uint4 v1 = hb8[(size_t)s1 * 8 + lq3];
            uint4 v2 = hb8[(size_t)s2 * 8 + lq3];
            uint4 v3 = hb8[(size_t)s3 * 8 + lq3];
            ACC8(v0); ACC8(v1); ACC8(v2); ACC8(v3);
            if (take > 32) {                       // wave-uniform branch
                int s4 = __shfl(myid, 32 + lg3);
                int s5 = __shfl(myid, 40 + lg3);
                int s6 = __shfl(myid, 48 + lg3);
                int s7 = __shfl(myid, 56 + lg3);
                uint4 w0 = hb8[(size_t)s4 * 8 + lq3];
                uint4 w1 = hb8[(size_t)s5 * 8 + lq3];
                uint4 w2 = hb8[(size_t)s6 * 8 + lq3];
                uint4 w3 = hb8[(size_t)s7 * 8 + lq3];
                ACC8(w0); ACC8(w1); ACC8(w2); ACC8(w3);
            }
            j += take;
        }
        // butterfly-reduce over the 8 edge groups (lanes with equal lq3)
#define RED8(F)                     \
        F += __shfl_xor(F, 8);      \
        F += __shfl_xor(F, 16);     \
        F += __shfl_xor(F, 32);
        RED8(f0) RED8(f1) RED8(f2) RED8(f3) RED8(f4) RED8(f5) RED8(f6) RED8(f7)
#undef RED8
        float a0, a1, a2, a3, a4;
        if (L0) {
            // full 64-lane butterfly (each lane held distinct edge slots)
#pragma unroll
            for (int off = 1; off < 64; off <<= 1) {
                e0 += __shfl_xor(e0, off);
                e1 += __shfl_xor(e1, off);
                e2 += __shfl_xor(e2, off);
                e3 += __shfl_xor(e3, off);
                e4 += __shfl_xor(e4, off);
            }
            a0 = e0; a1 = e1; a2 = e2; a3 = e3; a4 = e4;
            if (lane < EFD) {
                float v = (lane == 0) ? e0 : (lane == 1) ? e1 : (lane == 2) ? e2
                        : (lane == 3) ? e3 : e4;
                aggE[(size_t)n * EFD + lane] = v;
            }
        } else {
            a0 = aggE[n * 5 + 0]; a1 = aggE[n * 5 + 1]; a2 = aggE[n * 5 + 2];
            a3 = aggE[n * 5 + 3]; a4 = aggE[n * 5 + 4];
        }
        // redistribute: lane lq (0..15) wants features [4lq,4lq+4) = chunk lq>>1,
        // half (lq&1). Post-butterfly every lane holds full sums of chunk lane&7.
        int srcl = lq >> 1;
        float x0 = __shfl(f0, srcl), x4 = __shfl(f4, srcl);
        float x1 = __shfl(f1, srcl), x5 = __shfl(f5, srcl);
        float x2 = __shfl(f2, srcl), x6 = __shfl(f6, srcl);
        float x3 = __shfl(f3, srcl), x7 = __shfl(f7, srcl);
        bool hiHalf = (lq & 1) != 0;
        float4 acc;
        acc.x = hiHalf ? x4 : x0;
        acc.y = hiHalf ? x5 : x1;
        acc.z = hiHalf ? x6 : x2;
        acc.w = hiHalf ? x7 : x3;
        // epilogue: + h[n] + (aggE[n] + selfloop) @ eW + (deg+1)*eb
        float c0 = a0 + 8.f;
        float ce = (float)(j1 - j0) + 1.f;
        float4 bb = bf4(hb4[(size_t)n * 16 + lq]);
        bb.x = fmaf(c0, ew0.x, bb.x); bb.y = fmaf(c0, ew0.y, bb.y);
        bb.z = fmaf(c0, ew0.z, bb.z); bb.w = fmaf(c0, ew0.w, bb.w);
        bb.x = fmaf(a1, ew1.x, bb.x); bb.y = fmaf(a1, ew1.y, bb.y);
        bb.z = fmaf(a1, ew1.z, bb.z); bb.w = fmaf(a1, ew1.w, bb.w);
        bb.x = fmaf(a2, ew2.x, bb.x); bb.y = fmaf(a2, ew2.y, bb.y);
        bb.z = fmaf(a2, ew2.z, bb.z); bb.w = fmaf(a2, ew2.w, bb.w);
        bb.x = fmaf(a3, ew3.x, bb.x); bb.y = fmaf(a3, ew3.y, bb.y);
        bb.z = fmaf(a3, ew3.z, bb.z); bb.w = fmaf(a3, ew3.w, bb.w);
        bb.x = fmaf(a4, ew4.x, bb.x); bb.y = fmaf(a4, ew4.y, bb.y);
        bb.z = fmaf(a4, ew4.z, bb.z); bb.w = fmaf(a4, ew4.w, bb.w);
        bb.x = fmaf(ce, eb4.x, bb.x); bb.y = fmaf(ce, eb4.y, bb.y);
        bb.z = fmaf(ce, eb4.z, bb.z); bb.w = fmaf(ce, eb4.w, bb.w);
        if (lg == 0) {
            ((float4*)agg)[(size_t)n * 16 + lq] =
                make_float4(acc.x + bb.x, acc.y + bb.y, acc.z + bb.z, acc.w + bb.w);
        }
    }
}
#undef ACC8

// Fused MLP via MFMA. 64-node tile, 4 waves; each wave owns 16 rows.
__global__ __launch_bounds__(256) void k_mlp(const float* __restrict__ agg,
                                             float* __restrict__ h2,
                                             const unsigned short* __restrict__ pw1,
                                             const float* __restrict__ b1l,
                                             const unsigned short* __restrict__ pw2,
                                             const float* __restrict__ b2l,
                                             float* __restrict__ stats) {
    __shared__ __align__(16) unsigned short hid[64 * 136];  // [m][j], 17.4KB
    int tid = threadIdx.x;
    int w = tid >> 6, lane = tid & 63;
    int q = lane >> 4, l15 = lane & 15;
    int n0 = blockIdx.x * 64;
    // ---- phase 1: hidden = relu(agg @ W1 + b1), MFMA ----
    int mrow = n0 + 16 * w + l15;
    const float* arow = agg + (size_t)(mrow < N_NODES ? mrow : N_NODES - 1) * EMB;
    FragU fa[2];
#pragma unroll
    for (int s = 0; s < 2; ++s) {
        float4 x0 = *(const float4*)&arow[32 * s + 8 * q];
        float4 x1 = *(const float4*)&arow[32 * s + 8 * q + 4];
        fa[s].u[0] = f2bf(x0.x); fa[s].u[1] = f2bf(x0.y);
        fa[s].u[2] = f2bf(x0.z); fa[s].u[3] = f2bf(x0.w);
        fa[s].u[4] = f2bf(x1.x); fa[s].u[5] = f2bf(x1.y);
        fa[s].u[6] = f2bf(x1.z); fa[s].u[7] = f2bf(x1.w);
    }
    const uint4* w1f = (const uint4*)pw1;
    f4_t acc1[8];
#pragma unroll
    for (int t = 0; t < 8; ++t) {
        acc1[t] = (f4_t){0.f, 0.f, 0.f, 0.f};
        FragU b0, b1;
        b0.q = w1f[(t * 2 + 0) * 64 + lane];
        b1.q = w1f[(t * 2 + 1) * 64 + lane];
        acc1[t] = __builtin_amdgcn_mfma_f32_16x16x32_bf16(fa[0].v, b0.v, acc1[t], 0, 0, 0);
        acc1[t] = __builtin_amdgcn_mfma_f32_16x16x32_bf16(fa[1].v, b1.v, acc1[t], 0, 0, 0);
    }
#pragma unroll
    for (int t = 0; t < 8; ++t) {
        int col = 16 * t + l15;
        float bv = b1l[col];
#pragma unroll
        for (int r = 0; r < 4; ++r) {
            int m = 16 * w + q * 4 + r;
            hid[m * 136 + col] = f2bf(fmaxf(acc1[t][r] + bv, 0.f));
        }
    }
    // ---- phase 2: h2 = hidden @ W2 + b2 (wave-local hid, no barrier needed) ----
    FragU fa2[4];
#pragma unroll
    for (int s = 0; s < 4; ++s)
        fa2[s].q = *(const uint4*)&hid[(16 * w + l15) * 136 + 32 * s + 8 * q];
    const uint4* w2f = (const uint4*)pw2;
    f4_t acc2[4];
#pragma unroll
    for (int t = 0; t < 4; ++t) {
        acc2[t] = (f4_t){0.f, 0.f, 0.f, 0.f};
#pragma unroll
        for (int s = 0; s < 4; ++s) {
            FragU b;
            b.q = w2f[(t * 4 + s) * 64 + lane];
            acc2[t] = __builtin_amdgcn_mfma_f32_16x16x32_bf16(fa2[s].v, b.v, acc2[t], 0, 0, 0);
        }
    }
    float sacc[4] = {0.f, 0.f, 0.f, 0.f}, qacc[4] = {0.f, 0.f, 0.f, 0.f};
#pragma unroll
    for (int t = 0; t < 4; ++t) {
        int col = 16 * t + l15;
        float bv = b2l[col];
#pragma unroll
        for (int r = 0; r < 4; ++r) {
            int nn = n0 + 16 * w + q * 4 + r;
            if (nn < N_NODES) {
                float v = acc2[t][r] + bv;
                h2[(size_t)nn * EMB + col] = v;
                sacc[t] += v;
                qacc[t] = fmaf(v, v, qacc[t]);
            }
        }
    }
#pragma unroll
    for (int t = 0; t < 4; ++t) {
        sacc[t] += __shfl_xor(sacc[t], 16); qacc[t] += __shfl_xor(qacc[t], 16);
        sacc[t] += __shfl_xor(sacc[t], 32); qacc[t] += __shfl_xor(qacc[t], 32);
    }
    __syncthreads();  // all waves done with hid; reuse as float scratch (2KB)
    float* red = (float*)hid;
    if (q == 0) {
#pragma unroll
        for (int t = 0; t < 4; ++t) {
            red[w * 64 + 16 * t + l15] = sacc[t];
            red[256 + w * 64 + 16 * t + l15] = qacc[t];
        }
    }
    __syncthreads();
    if (tid < 64) {
        float s = red[tid] + red[64 + tid] + red[128 + tid] + red[192 + tid];
        float qq = red[256 + tid] + red[320 + tid] + red[384 + tid] + red[448 + tid];
        atomAddF(&stats[tid], s);
        atomAddF(&stats[64 + tid], qq);
    }
}

// BN apply + ELU (layers 0,1): h(bf16) = elu(bn(h2))
__global__ void k_bn(const float* __restrict__ h2, unsigned short* __restrict__ h,
                     const float* __restrict__ stats, const float* __restrict__ gam,
                     const float* __restrict__ bet) {
    int gid = blockIdx.x * 256 + threadIdx.x;
    if (gid >= N_NODES * EMB) return;
    int f = gid & 63;
    const float invN = 1.f / (float)N_NODES;
    float mean = stats[f] * invN;
    float var = stats[64 + f] * invN - mean * mean;
    float inv = rsqrtf(var + BN_EPS);
    float v = (h2[gid] - mean) * inv * gam[f] + bet[f];
    h[gid] = f2bf(v > 0.f ? v : expm1f(v));
}

// last layer: BN only for the 250 super-nodes (h2 stays fp32)
__global__ void k_bnout(const float* __restrict__ h2, const int* __restrict__ last,
                        const float* __restrict__ stats, const float* __restrict__ gam,
                        const float* __restrict__ bet, float* __restrict__ out) {
    int gid = blockIdx.x * 256 + threadIdx.x;
    if (gid >= NGRAPH * EMB) return;
    int b = gid >> 6, f = gid & 63;
    const float invN = 1.f / (float)N_NODES;
    float mean = stats[f] * invN;
    float var = stats[64 + f] * invN - mean * mean;
    float inv = rsqrtf(var + BN_EPS);
    out[gid] = (h2[last[b] * EMB + f] - mean) * inv * gam[f] + bet[f];
}

extern "C" void kernel_launch(void* const* d_in, const int* in_sizes, int n_in,
                              void* d_out, int out_size, void* d_ws, size_t ws_size,
                              hipStream_t stream) {
    const float* x   = (const float*)d_in[0];
    const float* ea  = (const float*)d_in[1];
    const int*   eidx= (const int*)d_in[2];
    const int*   last= (const int*)d_in[3];
    const float* xW  = (const float*)d_in[4];
    const float* xb  = (const float*)d_in[5];
    const float* eW  = (const float*)d_in[6];
    const float* eb  = (const float*)d_in[7];
    const float* W1  = (const float*)d_in[8];
    const float* b1  = (const float*)d_in[9];
    const float* W2  = (const float*)d_in[10];
    const float* b2  = (const float*)d_in[11];
    const float* gam = (const float*)d_in[12];
    const float* bet = (const float*)d_in[13];
    float* out = (float*)d_out;

    const int* srcI = eidx;
    const int* dstI = eidx + N_EDGES;

    float* hslot  = (float*)d_ws;                 // h bf16 (N+1 rows), uses half
    float* agg    = hslot + (N_NODES + 1) * EMB;  // N*64 f32 (h2 in loop)
    float* aggE   = agg + N_NODES * EMB;
    float* stats  = aggE + N_NODES * EFD;
    int* rowstart = (int*)(stats + NLAYER * 2 * EMB);
    int* csr      = rowstart + N_NODES + 1;
    int* csrE     = csr + N_EDGES;
    int* cntmat   = csrE + N_EDGES;
    int* off2     = cntmat + CNTM;
    unsigned short* pw1 = (unsigned short*)(off2 + CNTM); // 3*8192 bf16
    unsigned short* pw2 = pw1 + NLAYER * EMB * HID;       // 3*8192 bf16
    unsigned short* h = (unsigned short*)hslot;
    int2* bufSD   = (int2*)agg;                // alias, dead before layer loop

    k_prep<<<INPB + PACKB + 1, 256, 0, stream>>>(x, xW, xb, h, W1, W2, pw1, pw2, stats);
    k_binA<<<NCHK, 256, 0, stream>>>(dstI, cntmat);
    k_scan<<<1, 1024, 0, stream>>>(cntmat, off2);
    k_binC<<<NCHK, 256, 0, stream>>>(srcI, dstI, off2, bufSD);
    k_binD<<<NBKT, 256, 0, stream>>>(bufSD, off2, csr, csrE, rowstart);

    const int aggBlocks = ((N_NODES + 1) / 2 * 64 + 255) / 256;  // 2 nodes/wave
    const int mlpBlocks = (N_NODES + 63) / 64;                   // 782
    for (int l = 0; l < NLAYER; ++l) {
        if (l == 0)
            k_agg<1><<<aggBlocks, 256, 0, stream>>>(
                h, agg, rowstart, csr, csrE, ea, aggE, eW + l * EFD * EMB, eb + l * EMB);
        else
            k_agg<0><<<aggBlocks, 256, 0, stream>>>(
                h, agg, rowstart, csr, csrE, ea, aggE, eW + l * EFD * EMB, eb + l * EMB);
        k_mlp<<<mlpBlocks, 256, 0, stream>>>(agg, agg, pw1 + l * EMB * HID, b1 + l * HID,
                                             pw2 + l * HID * EMB, b2 + l * EMB,
                                             stats + l * 2 * EMB);
        if (l < NLAYER - 1) {
            k_bn<<<(N_NODES * EMB + 255) / 256, 256, 0, stream>>>(
                agg, h, stats + l * 2 * EMB, gam + l * EMB, bet + l * EMB);
        } else {
            k_bnout<<<(NGRAPH * EMB + 255) / 256, 256, 0, stream>>>(
                agg, last, stats + l * 2 * EMB, gam + l * EMB, bet + l * EMB, out);
        }
    }
}

// Round 4
// 355.706 us; speedup vs baseline: 1.0877x; 1.0877x over previous
//
#include <hip/hip_runtime.h>

#define N_NODES 50000
#define N_EDGES 1000000
#define EMB     64
#define HID     128
#define NLAYER  3
#define NGRAPH  250
#define XFD     7
#define EFD     5
#define BN_EPS  1e-5f

// two-level counting sort geometry
#define BKT_SH 8
#define BKT_SZ 256
#define NBKT   ((N_NODES + BKT_SZ - 1) / BKT_SZ)  // 196
#define CHKE   4096
#define NCHK   ((N_EDGES + CHKE - 1) / CHKE)      // 245
#define CNTM   (NBKT * NCHK)                      // 48020 (= 4*12005)
#define INPB   ((((N_NODES + 1) * EMB) + 255) / 256)   // 12501
#define PACKB  ((NLAYER * 2 * EMB * HID + 255) / 256)  // 192

typedef short bf8_t __attribute__((ext_vector_type(8)));   // 8 bf16 (4 VGPRs)
typedef float f4_t  __attribute__((ext_vector_type(4)));   // MFMA acc

union FragU {
    uint4 q;
    bf8_t v;
    unsigned short u[8];
};

__device__ __forceinline__ void atomAddF(float* p, float v) {
    __hip_atomic_fetch_add(p, v, __ATOMIC_RELAXED, __HIP_MEMORY_SCOPE_AGENT);
}

__device__ __forceinline__ unsigned short f2bf(float f) {
    unsigned int u = __float_as_uint(f);
    u += 0x7fffu + ((u >> 16) & 1u);
    return (unsigned short)(u >> 16);
}
__device__ __forceinline__ float bf2f(unsigned short s) {
    return __uint_as_float(((unsigned int)s) << 16);
}
__device__ __forceinline__ float4 bf4(ushort4 u) {
    return make_float4(bf2f(u.x), bf2f(u.y), bf2f(u.z), bf2f(u.w));
}

// Fused one-time prep: h = x@xW+xb (+ zero row N_NODES), W1/W2 pack into
// MFMA B-frag order, stats zero. Block-range dispatch kills 2 launches + memset.
__global__ void k_prep(const float* __restrict__ x, const float* __restrict__ xW,
                       const float* __restrict__ xb, unsigned short* __restrict__ h,
                       const float* __restrict__ W1, const float* __restrict__ W2,
                       unsigned short* __restrict__ pw1, unsigned short* __restrict__ pw2,
                       float* __restrict__ stats) {
    int bid = blockIdx.x;
    if (bid < INPB) {
        int gid = bid * 256 + threadIdx.x;
        if (gid >= (N_NODES + 1) * EMB) return;
        int n = gid >> 6, f = gid & 63;
        if (n == N_NODES) { h[gid] = 0; return; }
        float acc = xb[f];
#pragma unroll
        for (int k = 0; k < XFD; ++k) acc = fmaf(x[n * XFD + k], xW[k * EMB + f], acc);
        h[gid] = f2bf(acc);
    } else if (bid < INPB + PACKB) {
        int gid = (bid - INPB) * 256 + threadIdx.x;    // 3*16384 total
        int layer = gid >> 14;
        int r = gid & 16383;
        if (layer >= NLAYER) return;
        if (r < 8192) {
            int p = r;
            int j = p & 7, lane = (p >> 3) & 63, ts = p >> 9;  // ts<16
            int t = ts >> 1, s = ts & 1;
            int k = 32 * s + 8 * (lane >> 4) + j;
            int n = 16 * t + (lane & 15);
            pw1[layer * 8192 + p] = f2bf(W1[layer * EMB * HID + k * HID + n]);
        } else {
            int p = r - 8192;
            int j = p & 7, lane = (p >> 3) & 63, ts = p >> 9;  // ts<16
            int t = ts >> 2, s = ts & 3;
            int k = 32 * s + 8 * (lane >> 4) + j;
            int n = 16 * t + (lane & 15);
            pw2[layer * 8192 + p] = f2bf(W2[layer * HID * EMB + k * EMB + n]);
        }
    } else {
        for (int i = threadIdx.x; i < NLAYER * 2 * EMB; i += 256) stats[i] = 0.f;
    }
}

// ---- phase A: per-chunk coarse-bucket histogram ----
__global__ __launch_bounds__(256) void k_binA(const int* __restrict__ dst,
                                              int* __restrict__ cntmat) {
    __shared__ int hist[NBKT];
    int tid = threadIdx.x, c = blockIdx.x;
    for (int i = tid; i < NBKT; i += 256) hist[i] = 0;
    __syncthreads();
    int e0 = c * CHKE, e1 = min(e0 + CHKE, N_EDGES);
    for (int i = e0 + tid; i < e1; i += 256) atomicAdd(&hist[dst[i] >> BKT_SH], 1);
    __syncthreads();
    for (int b = tid; b < NBKT; b += 256) cntmat[b * NCHK + c] = hist[b];
}

// ---- single-block chained exclusive scan, int4-vectorized (12 rounds) ----
__global__ __launch_bounds__(1024) void k_scan(const int* __restrict__ in,
                                               int* __restrict__ out) {
    __shared__ int wsum[16];
    int tid = threadIdx.x, lane = tid & 63, wid = tid >> 6;
    int carry = 0;
    const int4* in4 = (const int4*)in;
    int4* out4 = (int4*)out;
    const int n4 = CNTM / 4;  // 12005
    for (int base = 0; base < n4; base += 1024) {
        int i = base + tid;
        int4 v = make_int4(0, 0, 0, 0);
        if (i < n4) v = in4[i];
        int t = v.x + v.y + v.z + v.w;
        int x = t;
#pragma unroll
        for (int off = 1; off < 64; off <<= 1) {
            int y = __shfl_up(x, off);
            if (lane >= off) x += y;
        }
        if (lane == 63) wsum[wid] = x;
        __syncthreads();
        int woff = 0, tot = 0;
#pragma unroll
        for (int w = 0; w < 16; ++w) {
            int s = wsum[w];
            if (w < wid) woff += s;
            tot += s;
        }
        if (i < n4) {
            int ex = carry + woff + x - t;
            out4[i] = make_int4(ex, ex + v.x, ex + v.x + v.y, ex + v.x + v.y + v.z);
        }
        carry += tot;
        __syncthreads();
    }
}

// ---- phase C: coarse scatter of packed {src, d_local<<20|eid} ----
__global__ __launch_bounds__(256) void k_binC(const int* __restrict__ src,
                                              const int* __restrict__ dst,
                                              const int* __restrict__ off2,
                                              int2* __restrict__ bufSD) {
    __shared__ int cur[NBKT];
    int tid = threadIdx.x, c = blockIdx.x;
    for (int b = tid; b < NBKT; b += 256) cur[b] = off2[b * NCHK + c];
    __syncthreads();
    int e0 = c * CHKE, e1 = min(e0 + CHKE, N_EDGES);
    for (int i = e0 + tid; i < e1; i += 256) {
        int d = dst[i];
        int b = d >> BKT_SH;
        int p = atomicAdd(&cur[b], 1);
        bufSD[p] = make_int2(src[i], ((d & (BKT_SZ - 1)) << 20) | i);
    }
}

// ---- phase D: per-bucket fine sort -> csr + csrE + rowstart ----
__global__ __launch_bounds__(256) void k_binD(const int2* __restrict__ bufSD,
                                              const int* __restrict__ off2,
                                              int* __restrict__ csr,
                                              int* __restrict__ csrE,
                                              int* __restrict__ rowstart) {
    __shared__ int hist[BKT_SZ];
    __shared__ int cur[BKT_SZ];
    __shared__ int wtot[4];
    int tid = threadIdx.x, b = blockIdx.x;
    int bstart = off2[b * NCHK];
    int bend = (b + 1 < NBKT) ? off2[(b + 1) * NCHK] : N_EDGES;
    hist[tid] = 0;
    __syncthreads();
    for (int j = bstart + tid; j < bend; j += 256)
        atomicAdd(&hist[bufSD[j].y >> 20], 1);
    __syncthreads();
    int lane = tid & 63, wid = tid >> 6;
    int v = hist[tid], x = v;
#pragma unroll
    for (int off = 1; off < 64; off <<= 1) {
        int y = __shfl_up(x, off);
        if (lane >= off) x += y;
    }
    if (lane == 63) wtot[wid] = x;
    __syncthreads();
    int woff = 0;
    for (int w = 0; w < wid; ++w) woff += wtot[w];
    int ex = woff + x - v;
    cur[tid] = ex;
    int node = b * BKT_SZ + tid;
    if (node < N_NODES) rowstart[node] = bstart + ex;
    if (b == NBKT - 1 && tid == 0) rowstart[N_NODES] = N_EDGES;
    __syncthreads();
    for (int j = bstart + tid; j < bend; j += 256) {
        int2 t = bufSD[j];
        int local = t.y >> 20;
        int p = atomicAdd(&cur[local], 1);
        csr[bstart + p] = t.x;
        csrE[bstart + p] = t.y & 0xFFFFF;
    }
}

// agg(f32): wave handles 4 consecutive nodes (R3 lesson: k_agg is NOT
// latency-bound — it is throughput-bound on the L2-miss path (h=6.4MB vs
// 4MiB/XCD L2, ~120MB FETCH); 2 nodes/wave only added overhead, 49 vs <44us).
// uint4 gathers: row of 64 bf16 read by 8 lanes, 8 edges per load instr,
// 4/8 loads unconditionally in flight. Invalid slots -> zero row h[N_NODES].
// L0: ea aggregation fused into the edge loop (kills the k_aggE kernel).
#define ACC8(v)                                                         \
    do {                                                                \
        f0 += __uint_as_float((v).x << 16);                             \
        f1 += __uint_as_float((v).x & 0xffff0000u);                     \
        f2 += __uint_as_float((v).y << 16);                             \
        f3 += __uint_as_float((v).y & 0xffff0000u);                     \
        f4 += __uint_as_float((v).z << 16);                             \
        f5 += __uint_as_float((v).z & 0xffff0000u);                     \
        f6 += __uint_as_float((v).w << 16);                             \
        f7 += __uint_as_float((v).w & 0xffff0000u);                     \
    } while (0)

template <int L0>
__global__ __launch_bounds__(256) void k_agg(const unsigned short* __restrict__ h,
                                             float* __restrict__ agg,
                                             const int* __restrict__ rowstart,
                                             const int* __restrict__ csr,
                                             const int* __restrict__ csrE,
                                             const float* __restrict__ ea,
                                             float* __restrict__ aggE,
                                             const float* __restrict__ eWl,
                                             const float* __restrict__ ebl) {
    int wave = (blockIdx.x * 256 + threadIdx.x) >> 6;
    int lane = threadIdx.x & 63;
    int nbase = wave * 4;
    if (nbase >= N_NODES) return;
    int lg3 = lane >> 3, lq3 = lane & 7;   // edge slot / uint4 chunk
    int lg = lane >> 4, lq = lane & 15;    // epilogue layout (float4 per lq)
    const uint4* hb8 = (const uint4*)h;        // 8 uint4 per 64-bf16 row
    const ushort4* hb4 = (const ushort4*)h;    // 16 ushort4 per row
    const float4* eW4 = (const float4*)eWl;
    float4 ew0 = eW4[lq], ew1 = eW4[16 + lq], ew2 = eW4[32 + lq],
           ew3 = eW4[48 + lq], ew4 = eW4[64 + lq];
    float4 eb4 = ((const float4*)ebl)[lq];
    int nend = min(nbase + 4, N_NODES);
    for (int n = nbase; n < nend; ++n) {
        int j0 = rowstart[n], j1 = rowstart[n + 1];
        float f0 = 0.f, f1 = 0.f, f2 = 0.f, f3 = 0.f,
              f4 = 0.f, f5 = 0.f, f6 = 0.f, f7 = 0.f;
        float e0 = 0.f, e1 = 0.f, e2 = 0.f, e3 = 0.f, e4 = 0.f;
        for (int j = j0; j < j1;) {
            int take = j1 - j;
            if (take > 64) take = 64;
            int myid = (lane < take) ? csr[j + lane] : N_NODES;  // zero row
            if (L0) {
                if (lane < take) {
                    const float* p = ea + (size_t)csrE[j + lane] * EFD;
                    e0 += p[0]; e1 += p[1]; e2 += p[2]; e3 += p[3]; e4 += p[4];
                }
            }
            int s0 = __shfl(myid, lg3);
            int s1 = __shfl(myid, 8 + lg3);
            int s2 = __shfl(myid, 16 + lg3);
            int s3 = __shfl(myid, 24 + lg3);
            uint4 v0 = hb8[(size_t)s0 * 8 + lq3];
            uint4 v1 = hb8[(size_t)s1 * 8 + lq3];
            uint4 v2 = hb8[(size_t)s2 * 8 + lq3];
            uint4 v3 = hb8[(size_t)s3 * 8 + lq3];
            ACC8(v0); ACC8(v1); ACC8(v2); ACC8(v3);
            if (take > 32) {                       // wave-uniform branch
                int s4 = __shfl(myid, 32 + lg3);
                int s5 = __shfl(myid, 40 + lg3);
                int s6 = __shfl(myid, 48 + lg3);
                int s7 = __shfl(myid, 56 + lg3);
                uint4 w0 = hb8[(size_t)s4 * 8 + lq3];
                uint4 w1 = hb8[(size_t)s5 * 8 + lq3];
                uint4 w2 = hb8[(size_t)s6 * 8 + lq3];
                uint4 w3 = hb8[(size_t)s7 * 8 + lq3];
                ACC8(w0); ACC8(w1); ACC8(w2); ACC8(w3);
            }
            j += take;
        }
        // butterfly-reduce over the 8 edge groups (lanes with equal lq3)
#define RED8(F)                     \
        F += __shfl_xor(F, 8);      \
        F += __shfl_xor(F, 16);     \
        F += __shfl_xor(F, 32);
        RED8(f0) RED8(f1) RED8(f2) RED8(f3) RED8(f4) RED8(f5) RED8(f6) RED8(f7)
#undef RED8
        float a0, a1, a2, a3, a4;
        if (L0) {
            // full 64-lane butterfly (each lane held distinct edge slots)
#pragma unroll
            for (int off = 1; off < 64; off <<= 1) {
                e0 += __shfl_xor(e0, off);
                e1 += __shfl_xor(e1, off);
                e2 += __shfl_xor(e2, off);
                e3 += __shfl_xor(e3, off);
                e4 += __shfl_xor(e4, off);
            }
            a0 = e0; a1 = e1; a2 = e2; a3 = e3; a4 = e4;
            if (lane < EFD) {
                float v = (lane == 0) ? e0 : (lane == 1) ? e1 : (lane == 2) ? e2
                        : (lane == 3) ? e3 : e4;
                aggE[(size_t)n * EFD + lane] = v;
            }
        } else {
            a0 = aggE[n * 5 + 0]; a1 = aggE[n * 5 + 1]; a2 = aggE[n * 5 + 2];
            a3 = aggE[n * 5 + 3]; a4 = aggE[n * 5 + 4];
        }
        // redistribute: lane lq (0..15) wants features [4lq,4lq+4) = chunk lq>>1,
        // half (lq&1). Post-butterfly every lane holds full sums of chunk lane&7.
        int srcl = lq >> 1;
        float x0 = __shfl(f0, srcl), x4 = __shfl(f4, srcl);
        float x1 = __shfl(f1, srcl), x5 = __shfl(f5, srcl);
        float x2 = __shfl(f2, srcl), x6 = __shfl(f6, srcl);
        float x3 = __shfl(f3, srcl), x7 = __shfl(f7, srcl);
        bool hiHalf = (lq & 1) != 0;
        float4 acc;
        acc.x = hiHalf ? x4 : x0;
        acc.y = hiHalf ? x5 : x1;
        acc.z = hiHalf ? x6 : x2;
        acc.w = hiHalf ? x7 : x3;
        // epilogue: + h[n] + (aggE[n] + selfloop) @ eW + (deg+1)*eb
        float c0 = a0 + 8.f;
        float ce = (float)(j1 - j0) + 1.f;
        float4 bb = bf4(hb4[(size_t)n * 16 + lq]);
        bb.x = fmaf(c0, ew0.x, bb.x); bb.y = fmaf(c0, ew0.y, bb.y);
        bb.z = fmaf(c0, ew0.z, bb.z); bb.w = fmaf(c0, ew0.w, bb.w);
        bb.x = fmaf(a1, ew1.x, bb.x); bb.y = fmaf(a1, ew1.y, bb.y);
        bb.z = fmaf(a1, ew1.z, bb.z); bb.w = fmaf(a1, ew1.w, bb.w);
        bb.x = fmaf(a2, ew2.x, bb.x); bb.y = fmaf(a2, ew2.y, bb.y);
        bb.z = fmaf(a2, ew2.z, bb.z); bb.w = fmaf(a2, ew2.w, bb.w);
        bb.x = fmaf(a3, ew3.x, bb.x); bb.y = fmaf(a3, ew3.y, bb.y);
        bb.z = fmaf(a3, ew3.z, bb.z); bb.w = fmaf(a3, ew3.w, bb.w);
        bb.x = fmaf(a4, ew4.x, bb.x); bb.y = fmaf(a4, ew4.y, bb.y);
        bb.z = fmaf(a4, ew4.z, bb.z); bb.w = fmaf(a4, ew4.w, bb.w);
        bb.x = fmaf(ce, eb4.x, bb.x); bb.y = fmaf(ce, eb4.y, bb.y);
        bb.z = fmaf(ce, eb4.z, bb.z); bb.w = fmaf(ce, eb4.w, bb.w);
        if (lg == 0) {
            ((float4*)agg)[(size_t)n * 16 + lq] =
                make_float4(acc.x + bb.x, acc.y + bb.y, acc.z + bb.z, acc.w + bb.w);
        }
    }
}
#undef ACC8

// Fused MLP via MFMA. 64-node tile, 4 waves; each wave owns 16 rows.
__global__ __launch_bounds__(256) void k_mlp(const float* __restrict__ agg,
                                             float* __restrict__ h2,
                                             const unsigned short* __restrict__ pw1,
                                             const float* __restrict__ b1l,
                                             const unsigned short* __restrict__ pw2,
                                             const float* __restrict__ b2l,
                                             float* __restrict__ stats) {
    __shared__ __align__(16) unsigned short hid[64 * 136];  // [m][j], 17.4KB
    int tid = threadIdx.x;
    int w = tid >> 6, lane = tid & 63;
    int q = lane >> 4, l15 = lane & 15;
    int n0 = blockIdx.x * 64;
    // ---- phase 1: hidden = relu(agg @ W1 + b1), MFMA ----
    int mrow = n0 + 16 * w + l15;
    const float* arow = agg + (size_t)(mrow < N_NODES ? mrow : N_NODES - 1) * EMB;
    FragU fa[2];
#pragma unroll
    for (int s = 0; s < 2; ++s) {
        float4 x0 = *(const float4*)&arow[32 * s + 8 * q];
        float4 x1 = *(const float4*)&arow[32 * s + 8 * q + 4];
        fa[s].u[0] = f2bf(x0.x); fa[s].u[1] = f2bf(x0.y);
        fa[s].u[2] = f2bf(x0.z); fa[s].u[3] = f2bf(x0.w);
        fa[s].u[4] = f2bf(x1.x); fa[s].u[5] = f2bf(x1.y);
        fa[s].u[6] = f2bf(x1.z); fa[s].u[7] = f2bf(x1.w);
    }
    const uint4* w1f = (const uint4*)pw1;
    f4_t acc1[8];
#pragma unroll
    for (int t = 0; t < 8; ++t) {
        acc1[t] = (f4_t){0.f, 0.f, 0.f, 0.f};
        FragU b0, b1;
        b0.q = w1f[(t * 2 + 0) * 64 + lane];
        b1.q = w1f[(t * 2 + 1) * 64 + lane];
        acc1[t] = __builtin_amdgcn_mfma_f32_16x16x32_bf16(fa[0].v, b0.v, acc1[t], 0, 0, 0);
        acc1[t] = __builtin_amdgcn_mfma_f32_16x16x32_bf16(fa[1].v, b1.v, acc1[t], 0, 0, 0);
    }
#pragma unroll
    for (int t = 0; t < 8; ++t) {
        int col = 16 * t + l15;
        float bv = b1l[col];
#pragma unroll
        for (int r = 0; r < 4; ++r) {
            int m = 16 * w + q * 4 + r;
            hid[m * 136 + col] = f2bf(fmaxf(acc1[t][r] + bv, 0.f));
        }
    }
    // ---- phase 2: h2 = hidden @ W2 + b2 (wave-local hid, no barrier needed) ----
    FragU fa2[4];
#pragma unroll
    for (int s = 0; s < 4; ++s)
        fa2[s].q = *(const uint4*)&hid[(16 * w + l15) * 136 + 32 * s + 8 * q];
    const uint4* w2f = (const uint4*)pw2;
    f4_t acc2[4];
#pragma unroll
    for (int t = 0; t < 4; ++t) {
        acc2[t] = (f4_t){0.f, 0.f, 0.f, 0.f};
#pragma unroll
        for (int s = 0; s < 4; ++s) {
            FragU b;
            b.q = w2f[(t * 4 + s) * 64 + lane];
            acc2[t] = __builtin_amdgcn_mfma_f32_16x16x32_bf16(fa2[s].v, b.v, acc2[t], 0, 0, 0);
        }
    }
    float sacc[4] = {0.f, 0.f, 0.f, 0.f}, qacc[4] = {0.f, 0.f, 0.f, 0.f};
#pragma unroll
    for (int t = 0; t < 4; ++t) {
        int col = 16 * t + l15;
        float bv = b2l[col];
#pragma unroll
        for (int r = 0; r < 4; ++r) {
            int nn = n0 + 16 * w + q * 4 + r;
            if (nn < N_NODES) {
                float v = acc2[t][r] + bv;
                h2[(size_t)nn * EMB + col] = v;
                sacc[t] += v;
                qacc[t] = fmaf(v, v, qacc[t]);
            }
        }
    }
#pragma unroll
    for (int t = 0; t < 4; ++t) {
        sacc[t] += __shfl_xor(sacc[t], 16); qacc[t] += __shfl_xor(qacc[t], 16);
        sacc[t] += __shfl_xor(sacc[t], 32); qacc[t] += __shfl_xor(qacc[t], 32);
    }
    __syncthreads();  // all waves done with hid; reuse as float scratch (2KB)
    float* red = (float*)hid;
    if (q == 0) {
#pragma unroll
        for (int t = 0; t < 4; ++t) {
            red[w * 64 + 16 * t + l15] = sacc[t];
            red[256 + w * 64 + 16 * t + l15] = qacc[t];
        }
    }
    __syncthreads();
    if (tid < 64) {
        float s = red[tid] + red[64 + tid] + red[128 + tid] + red[192 + tid];
        float qq = red[256 + tid] + red[320 + tid] + red[384 + tid] + red[448 + tid];
        atomAddF(&stats[tid], s);
        atomAddF(&stats[64 + tid], qq);
    }
}

// BN apply + ELU (layers 0,1): h(bf16) = elu(bn(h2))
__global__ void k_bn(const float* __restrict__ h2, unsigned short* __restrict__ h,
                     const float* __restrict__ stats, const float* __restrict__ gam,
                     const float* __restrict__ bet) {
    int gid = blockIdx.x * 256 + threadIdx.x;
    if (gid >= N_NODES * EMB) return;
    int f = gid & 63;
    const float invN = 1.f / (float)N_NODES;
    float mean = stats[f] * invN;
    float var = stats[64 + f] * invN - mean * mean;
    float inv = rsqrtf(var + BN_EPS);
    float v = (h2[gid] - mean) * inv * gam[f] + bet[f];
    h[gid] = f2bf(v > 0.f ? v : expm1f(v));
}

// last layer: BN only for the 250 super-nodes (h2 stays fp32)
__global__ void k_bnout(const float* __restrict__ h2, const int* __restrict__ last,
                        const float* __restrict__ stats, const float* __restrict__ gam,
                        const float* __restrict__ bet, float* __restrict__ out) {
    int gid = blockIdx.x * 256 + threadIdx.x;
    if (gid >= NGRAPH * EMB) return;
    int b = gid >> 6, f = gid & 63;
    const float invN = 1.f / (float)N_NODES;
    float mean = stats[f] * invN;
    float var = stats[64 + f] * invN - mean * mean;
    float inv = rsqrtf(var + BN_EPS);
    out[gid] = (h2[last[b] * EMB + f] - mean) * inv * gam[f] + bet[f];
}

extern "C" void kernel_launch(void* const* d_in, const int* in_sizes, int n_in,
                              void* d_out, int out_size, void* d_ws, size_t ws_size,
                              hipStream_t stream) {
    const float* x   = (const float*)d_in[0];
    const float* ea  = (const float*)d_in[1];
    const int*   eidx= (const int*)d_in[2];
    const int*   last= (const int*)d_in[3];
    const float* xW  = (const float*)d_in[4];
    const float* xb  = (const float*)d_in[5];
    const float* eW  = (const float*)d_in[6];
    const float* eb  = (const float*)d_in[7];
    const float* W1  = (const float*)d_in[8];
    const float* b1  = (const float*)d_in[9];
    const float* W2  = (const float*)d_in[10];
    const float* b2  = (const float*)d_in[11];
    const float* gam = (const float*)d_in[12];
    const float* bet = (const float*)d_in[13];
    float* out = (float*)d_out;

    const int* srcI = eidx;
    const int* dstI = eidx + N_EDGES;

    float* hslot  = (float*)d_ws;                 // h bf16 (N+1 rows), uses half
    float* agg    = hslot + (N_NODES + 1) * EMB;  // N*64 f32 (h2 in loop)
    float* aggE   = agg + N_NODES * EMB;
    float* stats  = aggE + N_NODES * EFD;
    int* rowstart = (int*)(stats + NLAYER * 2 * EMB);
    int* csr      = rowstart + N_NODES + 4;       // pad: keep csr/cntmat 16B-aligned
    int* csrE     = csr + N_EDGES;
    int* cntmat   = csrE + N_EDGES;
    int* off2     = cntmat + CNTM;
    unsigned short* pw1 = (unsigned short*)(off2 + CNTM); // 3*8192 bf16
    unsigned short* pw2 = pw1 + NLAYER * EMB * HID;       // 3*8192 bf16
    unsigned short* h = (unsigned short*)hslot;
    int2* bufSD   = (int2*)agg;                // alias, dead before layer loop

    k_prep<<<INPB + PACKB + 1, 256, 0, stream>>>(x, xW, xb, h, W1, W2, pw1, pw2, stats);
    k_binA<<<NCHK, 256, 0, stream>>>(dstI, cntmat);
    k_scan<<<1, 1024, 0, stream>>>(cntmat, off2);
    k_binC<<<NCHK, 256, 0, stream>>>(srcI, dstI, off2, bufSD);
    k_binD<<<NBKT, 256, 0, stream>>>(bufSD, off2, csr, csrE, rowstart);

    const int aggBlocks = ((N_NODES + 3) / 4 * 64 + 255) / 256;  // 4 nodes/wave
    const int mlpBlocks = (N_NODES + 63) / 64;                   // 782
    for (int l = 0; l < NLAYER; ++l) {
        if (l == 0)
            k_agg<1><<<aggBlocks, 256, 0, stream>>>(
                h, agg, rowstart, csr, csrE, ea, aggE, eW + l * EFD * EMB, eb + l * EMB);
        else
            k_agg<0><<<aggBlocks, 256, 0, stream>>>(
                h, agg, rowstart, csr, csrE, ea, aggE, eW + l * EFD * EMB, eb + l * EMB);
        k_mlp<<<mlpBlocks, 256, 0, stream>>>(agg, agg, pw1 + l * EMB * HID, b1 + l * HID,
                                             pw2 + l * HID * EMB, b2 + l * EMB,
                                             stats + l * 2 * EMB);
        if (l < NLAYER - 1) {
            k_bn<<<(N_NODES * EMB + 255) / 256, 256, 0, stream>>>(
                agg, h, stats + l * 2 * EMB, gam + l * EMB, bet + l * EMB);
        } else {
            k_bnout<<<(NGRAPH * EMB + 255) / 256, 256, 0, stream>>>(
                agg, last, stats + l * 2 * EMB, gam + l * EMB, bet + l * EMB, out);
        }
    }
}